// Round 2
// baseline (792.320 us; speedup 1.0000x reference)
//
#include <hip/hip_runtime.h>

// ---------------- constants ----------------
#define BATCH   2
#define SEQLEN  1024
#define DMODEL  512
#define DSTATE  32
#define DINNER  1024
#define MROWS   (BATCH*SEQLEN)          // 2048
#define NPROJ   (2*DINNER + 2*DINNER*DSTATE)  // 67584

typedef short bf16x8 __attribute__((ext_vector_type(8)));
typedef float f32x4  __attribute__((ext_vector_type(4)));

__device__ __forceinline__ unsigned short f2bf(float f) {
    union { float f; unsigned u; } c; c.f = f;
    unsigned u = c.u;
    u += 0x7fffu + ((u >> 16) & 1u);   // RTNE
    return (unsigned short)(u >> 16);
}
__device__ __forceinline__ float bf2f(unsigned short h) {
    union { unsigned u; float f; } c; c.u = ((unsigned)h) << 16;
    return c.f;
}

// ---------------- cast fp32 -> bf16 (weights concat + x + Wout) ----------------
__global__ void cast_all(const float4* __restrict__ Wx, const float4* __restrict__ Wdt,
                         const float4* __restrict__ WB, const float4* __restrict__ WC,
                         const float4* __restrict__ x,  const float4* __restrict__ Wout,
                         unsigned short* __restrict__ Wbf,
                         unsigned short* __restrict__ Xbf,
                         unsigned short* __restrict__ Woutbf) {
    const long nWx = 131072, nWdt = 131072, nWB = 4194304, nWC = 4194304;
    const long nWall = nWx + nWdt + nWB + nWC;      // 8650752
    const long nX = 262144, nWo = 131072;
    const long total = nWall + nX + nWo;            // 9043968
    for (long u = (long)blockIdx.x * blockDim.x + threadIdx.x; u < total;
         u += (long)gridDim.x * blockDim.x) {
        float4 v; unsigned short* dst;
        if (u < nWall) {
            if (u < nWx)             v = Wx[u];
            else if (u < nWx+nWdt)   v = Wdt[u - nWx];
            else if (u < nWx+nWdt+nWB) v = WB[u - nWx - nWdt];
            else                     v = WC[u - nWx - nWdt - nWB];
            dst = Wbf + u*4;
        } else if (u < nWall + nX) {
            v = x[u - nWall];       dst = Xbf + (u - nWall)*4;
        } else {
            v = Wout[u - nWall - nX]; dst = Woutbf + (u - nWall - nX)*4;
        }
        ushort4 o; o.x = f2bf(v.x); o.y = f2bf(v.y); o.z = f2bf(v.z); o.w = f2bf(v.w);
        *(ushort4*)dst = o;
    }
}

// ---------------- bf16 MFMA GEMM: C[rows,N] = A[rows,K] * Bw[N,K]^T ----------------
// 128x128 tile, BK=32, 4 waves (2x2), each wave 64x64 via 4x4 frags of 16x16x32.
// Chunked over time: tile-row block rr0 = blockIdx.y*128 covers chunk-local rows
// [rr0, rr0+128) of a (2*Tchunk)-row chunk; b = rr0>=Tchunk; global row =
// b*SEQLEN + t0 + (rr0 - b*Tchunk) + local.
// EPI 0: projection epilogue (x_inner fp32 | delta=softplus(+bdt) fp32 | B bf16 | C bf16)
//        B/C stored at CHUNK-LOCAL rows; xin/dlt at GLOBAL rows.
// EPI 1: plain fp32 store to outf[globalrow*N + ncol]  (pass t0=0, Tchunk=MROWS)
template<int EPI>
__global__ __launch_bounds__(256)
void gemm_bt(const unsigned short* __restrict__ A, const unsigned short* __restrict__ Bw,
             int K, int N, int t0, int Tchunk,
             float* __restrict__ xin, float* __restrict__ dlt,
             unsigned short* __restrict__ Bout, unsigned short* __restrict__ Cout,
             const float* __restrict__ bdt, float* __restrict__ outf) {
    __shared__ unsigned short Asm[128*32];
    __shared__ unsigned short Bsm[128*32];
    const int tid  = threadIdx.x;
    const int w    = tid >> 6;
    const int lane = tid & 63;
    const int wm   = w >> 1, wn = w & 1;
    const int rr0  = blockIdx.y * 128;            // chunk-local row base of tile
    const int bb   = (rr0 >= Tchunk) ? 1 : 0;
    const int grow0 = bb * SEQLEN + t0 + (rr0 - bb * Tchunk);  // global row base
    const int n0   = blockIdx.x * 128;

    f32x4 acc[4][4] = {};

    const unsigned short* Ag = A  + (size_t)grow0 * K;
    const unsigned short* Bg = Bw + (size_t)n0 * K;

    const int c0 = w*64 + lane;       // chunk ids (16B units)
    const int c1 = c0 + 256;
    const int r   = lane & 15;
    const int h16 = lane >> 4;

    for (int k0 = 0; k0 < K; k0 += 32) {
        // stage A tile [128][32] and B tile [128][32] (linear LDS, 16B per lane)
        __builtin_amdgcn_global_load_lds(
            (const __attribute__((address_space(1))) void*)(Ag + (size_t)(c0>>2)*K + k0 + (c0&3)*8),
            (__attribute__((address_space(3))) void*)(Asm + w*512), 16, 0, 0);
        __builtin_amdgcn_global_load_lds(
            (const __attribute__((address_space(1))) void*)(Ag + (size_t)(c1>>2)*K + k0 + (c1&3)*8),
            (__attribute__((address_space(3))) void*)(Asm + 2048 + w*512), 16, 0, 0);
        __builtin_amdgcn_global_load_lds(
            (const __attribute__((address_space(1))) void*)(Bg + (size_t)(c0>>2)*K + k0 + (c0&3)*8),
            (__attribute__((address_space(3))) void*)(Bsm + w*512), 16, 0, 0);
        __builtin_amdgcn_global_load_lds(
            (const __attribute__((address_space(1))) void*)(Bg + (size_t)(c1>>2)*K + k0 + (c1&3)*8),
            (__attribute__((address_space(3))) void*)(Bsm + 2048 + w*512), 16, 0, 0);
        __syncthreads();

        bf16x8 af[4], bfr[4];
        #pragma unroll
        for (int i = 0; i < 4; i++) {
            af[i]  = *(const bf16x8*)(Asm + (wm*64 + i*16 + r)*32 + h16*8);
            bfr[i] = *(const bf16x8*)(Bsm + (wn*64 + i*16 + r)*32 + h16*8);
        }
        #pragma unroll
        for (int i = 0; i < 4; i++)
            #pragma unroll
            for (int j = 0; j < 4; j++)
                acc[i][j] = __builtin_amdgcn_mfma_f32_16x16x32_bf16(af[i], bfr[j], acc[i][j], 0, 0, 0);
        __syncthreads();
    }

    // epilogue: C/D layout col=lane&15, row=(lane>>4)*4+reg
    const int q = lane >> 4;
    #pragma unroll
    for (int i = 0; i < 4; i++) {
        #pragma unroll
        for (int j = 0; j < 4; j++) {
            const int lr0  = wm*64 + i*16 + q*4;   // local row within tile
            const int ncol = n0 + wn*64 + j*16 + r;
            #pragma unroll
            for (int t = 0; t < 4; t++) {
                const int lr = lr0 + t;
                const int mm = grow0 + lr;          // global row
                const int cr = rr0 + lr;            // chunk-local row
                const float v = acc[i][j][t];
                if (EPI == 0) {
                    if (ncol < 1024) {
                        xin[(size_t)mm*1024 + ncol] = v;
                    } else if (ncol < 2048) {
                        float z = v + bdt[ncol - 1024];
                        dlt[(size_t)mm*1024 + (ncol - 1024)] = (z > 20.f) ? z : log1pf(__expf(z));
                    } else if (ncol < 34816) {
                        Bout[(size_t)cr*32768 + (ncol - 2048)] = f2bf(v);
                    } else {
                        Cout[(size_t)cr*32768 + (ncol - 34816)] = f2bf(v);
                    }
                } else {
                    outf[(size_t)mm*N + ncol] = v;
                }
            }
        }
    }
}

// ---------------- sequential scan over t, parallel over (b,e,s) ----------------
// 32 lanes per (b,e) group; 8 groups per 256-thread block. Processes time
// steps [t0, t0+Tchunk); h carried across chunk launches in hbuf.
__global__ __launch_bounds__(256)
void scan_kernel(const float* __restrict__ dlt, const float* __restrict__ xin,
                 const unsigned short* __restrict__ Bbf, const unsigned short* __restrict__ Cbf,
                 const float* __restrict__ A_log, unsigned short* __restrict__ Ybf,
                 float* __restrict__ hbuf, int t0, int Tchunk, int first) {
    const int tid = threadIdx.x;
    const int g = tid >> 5;
    const int s = tid & 31;
    const int G = blockIdx.x * 8 + g;        // 0..2047
    const int b = G >> 10, e = G & 1023;

    const float Aes = -__expf(A_log[e*32 + s]);
    float h = first ? 0.f : hbuf[(size_t)G*32 + s];

    const size_t rowBC = (size_t)b*Tchunk*32768 + (size_t)e*32 + s;  // + lt*32768
    const size_t rowDX = (size_t)b*1024*1024 + e;                    // + (t0+lt)*1024

    const int CH = 8;
    float db[CH], xb[CH], bv[CH], cv[CH];
    #pragma unroll
    for (int j = 0; j < CH; j++) {
        db[j] = dlt[rowDX + (size_t)(t0 + j)*1024];
        xb[j] = xin[rowDX + (size_t)(t0 + j)*1024];
        bv[j] = bf2f(Bbf[rowBC + (size_t)j*32768]);
        cv[j] = bf2f(Cbf[rowBC + (size_t)j*32768]);
    }

    for (int tc = 0; tc < Tchunk; tc += CH) {
        float ndb[CH], nxb[CH], nbv[CH], ncv[CH];
        const bool more = (tc + CH) < Tchunk;
        if (more) {
            #pragma unroll
            for (int j = 0; j < CH; j++) {
                const size_t lt2 = tc + CH + j;
                ndb[j] = dlt[rowDX + (t0 + lt2)*1024];
                nxb[j] = xin[rowDX + (t0 + lt2)*1024];
                nbv[j] = bf2f(Bbf[rowBC + lt2*32768]);
                ncv[j] = bf2f(Cbf[rowBC + lt2*32768]);
            }
        }
        #pragma unroll
        for (int j = 0; j < CH; j++) {
            const float a = __expf(db[j] * Aes);
            h = a*h + bv[j]*xb[j];
            float p = cv[j]*h;
            p += __shfl_xor(p, 16, 32);
            p += __shfl_xor(p, 8, 32);
            p += __shfl_xor(p, 4, 32);
            p += __shfl_xor(p, 2, 32);
            p += __shfl_xor(p, 1, 32);
            if (s == 0) {
                const float y = p / (1.f + __expf(-p));  // SiLU
                Ybf[rowDX + (size_t)(t0 + tc + j)*1024] = f2bf(y);
            }
        }
        if (more) {
            #pragma unroll
            for (int j = 0; j < CH; j++) { db[j]=ndb[j]; xb[j]=nxb[j]; bv[j]=nbv[j]; cv[j]=ncv[j]; }
        }
    }
    hbuf[(size_t)G*32 + s] = h;
}

// ---------------- launch ----------------
extern "C" void kernel_launch(void* const* d_in, const int* in_sizes, int n_in,
                              void* d_out, int out_size, void* d_ws, size_t ws_size,
                              hipStream_t stream) {
    const float* x     = (const float*)d_in[0];
    const float* Wx    = (const float*)d_in[1];
    const float* Wdt   = (const float*)d_in[2];
    const float* bdt   = (const float*)d_in[3];
    const float* A_log = (const float*)d_in[4];
    const float* WB    = (const float*)d_in[5];
    const float* WC    = (const float*)d_in[6];
    const float* Wout  = (const float*)d_in[7];

    // ---- workspace layout (fixed part = 93,585,408 B) ----
    char* ws = (char*)d_ws;
    unsigned short* Wbf    = (unsigned short*)(ws);                 // 69,206,016 B
    unsigned short* Xbf    = (unsigned short*)(ws + 69206016);      //  2,097,152 B
    unsigned short* Woutbf = (unsigned short*)(ws + 71303168);      //  1,048,576 B
    float*          xin    = (float*)        (ws + 72351744);       //  8,388,608 B
    float*          dlt    = (float*)        (ws + 80740352);       //  8,388,608 B
    unsigned short* Ybf    = (unsigned short*)(ws + 89128960);      //  4,194,304 B
    float*          hbuf   = (float*)        (ws + 93323264);       //    262,144 B
    unsigned short* Bbf    = (unsigned short*)(ws + 93585408);      // T*131072 B
    // Cbf follows Bbf.

    // choose largest time-chunk T whose B/C buffers fit in the remaining ws
    const size_t fixedB = 93585408;
    int T = 128;
    const int cands[4] = {1024, 512, 256, 128};
    for (int ci = 0; ci < 4; ci++) {
        if (fixedB + (size_t)2 * cands[ci] * 131072 <= ws_size) { T = cands[ci]; break; }
    }
    unsigned short* Cbf = Bbf + (size_t)T * 65536;   // T*131072 bytes each

    cast_all<<<dim3(2048), dim3(256), 0, stream>>>(
        (const float4*)Wx, (const float4*)Wdt, (const float4*)WB, (const float4*)WC,
        (const float4*)x, (const float4*)Wout, Wbf, Xbf, Woutbf);

    const int NC = SEQLEN / T;
    for (int c = 0; c < NC; c++) {
        const int t0 = c * T;
        gemm_bt<0><<<dim3(NPROJ/128, 2*T/128), dim3(256), 0, stream>>>(
            Xbf, Wbf, DMODEL, NPROJ, t0, T, xin, dlt, Bbf, Cbf, bdt, nullptr);
        scan_kernel<<<dim3(MROWS/8), dim3(256), 0, stream>>>(
            dlt, xin, Bbf, Cbf, A_log, Ybf, hbuf, t0, T, (c == 0) ? 1 : 0);
    }

    gemm_bt<1><<<dim3(DMODEL/128, MROWS/128), dim3(256), 0, stream>>>(
        Ybf, Woutbf, DINNER, DMODEL, 0, MROWS, nullptr, nullptr, nullptr, nullptr, nullptr,
        (float*)d_out);
}

// Round 3
// 642.633 us; speedup vs baseline: 1.2329x; 1.2329x over previous
//
#include <hip/hip_runtime.h>

// ---------------- constants ----------------
#define BATCH   2
#define SEQLEN  1024
#define DMODEL  512
#define DSTATE  32
#define DINNER  1024
#define MROWS   (BATCH*SEQLEN)          // 2048
#define NPROJ   (2*DINNER + 2*DINNER*DSTATE)  // 67584

typedef short bf16x8 __attribute__((ext_vector_type(8)));
typedef float f32x4  __attribute__((ext_vector_type(4)));

__device__ __forceinline__ unsigned short f2bf(float f) {
    union { float f; unsigned u; } c; c.f = f;
    unsigned u = c.u;
    u += 0x7fffu + ((u >> 16) & 1u);   // RTNE
    return (unsigned short)(u >> 16);
}
__device__ __forceinline__ float bf2f(unsigned short h) {
    union { unsigned u; float f; } c; c.u = ((unsigned)h) << 16;
    return c.f;
}

// ---------------- cast fp32 -> bf16 (weights concat + x + Wout) ----------------
__global__ void cast_all(const float4* __restrict__ Wx, const float4* __restrict__ Wdt,
                         const float4* __restrict__ WB, const float4* __restrict__ WC,
                         const float4* __restrict__ x,  const float4* __restrict__ Wout,
                         unsigned short* __restrict__ Wbf,
                         unsigned short* __restrict__ Xbf,
                         unsigned short* __restrict__ Woutbf) {
    const long nWx = 131072, nWdt = 131072, nWB = 4194304, nWC = 4194304;
    const long nWall = nWx + nWdt + nWB + nWC;      // 8650752
    const long nX = 262144, nWo = 131072;
    const long total = nWall + nX + nWo;            // 9043968
    for (long u = (long)blockIdx.x * blockDim.x + threadIdx.x; u < total;
         u += (long)gridDim.x * blockDim.x) {
        float4 v; unsigned short* dst;
        if (u < nWall) {
            if (u < nWx)             v = Wx[u];
            else if (u < nWx+nWdt)   v = Wdt[u - nWx];
            else if (u < nWx+nWdt+nWB) v = WB[u - nWx - nWdt];
            else                     v = WC[u - nWx - nWdt - nWB];
            dst = Wbf + u*4;
        } else if (u < nWall + nX) {
            v = x[u - nWall];       dst = Xbf + (u - nWall)*4;
        } else {
            v = Wout[u - nWall - nX]; dst = Woutbf + (u - nWall - nX)*4;
        }
        ushort4 o; o.x = f2bf(v.x); o.y = f2bf(v.y); o.z = f2bf(v.z); o.w = f2bf(v.w);
        *(ushort4*)dst = o;
    }
}

// ---------------- bf16 MFMA GEMM: C[rows,N] = A[rows,K] * Bw[N,K]^T ----------------
// 128x128 tile, BK=32, 4 waves (2x2). XCD band swizzle: when nx%8==0, XCD
// x owns the contiguous n-band [x*nx/8, (x+1)*nx/8); within a band all row
// tiles of one n run back-to-back on the same XCD -> weight slab fetched once.
template<int EPI>
__global__ __launch_bounds__(256)
void gemm_bt(const unsigned short* __restrict__ A, const unsigned short* __restrict__ Bw,
             int K, int N, int t0, int Tchunk,
             float* __restrict__ xin, float* __restrict__ dlt,
             unsigned short* __restrict__ Bout, unsigned short* __restrict__ Cout,
             const float* __restrict__ bdt, float* __restrict__ outf) {
    __shared__ unsigned short Asm[128*32];
    __shared__ unsigned short Bsm[128*32];
    const int tid  = threadIdx.x;
    const int w    = tid >> 6;
    const int lane = tid & 63;
    const int wm   = w >> 1, wn = w & 1;

    // ---- XCD band swizzle ----
    const int nx = gridDim.x, ny = gridDim.y;
    int ntile, rtile;
    if ((nx & 7) == 0) {
        const int lin = blockIdx.x + nx * blockIdx.y;
        const int xcd = lin & 7;
        const int sl  = lin >> 3;
        ntile = xcd * (nx >> 3) + sl / ny;
        rtile = sl % ny;
    } else {
        ntile = blockIdx.x; rtile = blockIdx.y;
    }

    const int rr0  = rtile * 128;                 // chunk-local row base of tile
    const int bb   = (rr0 >= Tchunk) ? 1 : 0;
    const int grow0 = bb * SEQLEN + t0 + (rr0 - bb * Tchunk);  // global row base
    const int n0   = ntile * 128;

    f32x4 acc[4][4] = {};

    const unsigned short* Ag = A  + (size_t)grow0 * K;
    const unsigned short* Bg = Bw + (size_t)n0 * K;

    const int c0 = w*64 + lane;       // chunk ids (16B units)
    const int c1 = c0 + 256;
    const int r   = lane & 15;
    const int h16 = lane >> 4;

    for (int k0 = 0; k0 < K; k0 += 32) {
        __builtin_amdgcn_global_load_lds(
            (const __attribute__((address_space(1))) void*)(Ag + (size_t)(c0>>2)*K + k0 + (c0&3)*8),
            (__attribute__((address_space(3))) void*)(Asm + w*512), 16, 0, 0);
        __builtin_amdgcn_global_load_lds(
            (const __attribute__((address_space(1))) void*)(Ag + (size_t)(c1>>2)*K + k0 + (c1&3)*8),
            (__attribute__((address_space(3))) void*)(Asm + 2048 + w*512), 16, 0, 0);
        __builtin_amdgcn_global_load_lds(
            (const __attribute__((address_space(1))) void*)(Bg + (size_t)(c0>>2)*K + k0 + (c0&3)*8),
            (__attribute__((address_space(3))) void*)(Bsm + w*512), 16, 0, 0);
        __builtin_amdgcn_global_load_lds(
            (const __attribute__((address_space(1))) void*)(Bg + (size_t)(c1>>2)*K + k0 + (c1&3)*8),
            (__attribute__((address_space(3))) void*)(Bsm + 2048 + w*512), 16, 0, 0);
        __syncthreads();

        bf16x8 af[4], bfr[4];
        #pragma unroll
        for (int i = 0; i < 4; i++) {
            af[i]  = *(const bf16x8*)(Asm + (wm*64 + i*16 + r)*32 + h16*8);
            bfr[i] = *(const bf16x8*)(Bsm + (wn*64 + i*16 + r)*32 + h16*8);
        }
        #pragma unroll
        for (int i = 0; i < 4; i++)
            #pragma unroll
            for (int j = 0; j < 4; j++)
                acc[i][j] = __builtin_amdgcn_mfma_f32_16x16x32_bf16(af[i], bfr[j], acc[i][j], 0, 0, 0);
        __syncthreads();
    }

    // epilogue: C/D layout col=lane&15, row=(lane>>4)*4+reg
    const int q = lane >> 4;
    #pragma unroll
    for (int i = 0; i < 4; i++) {
        #pragma unroll
        for (int j = 0; j < 4; j++) {
            const int lr0  = wm*64 + i*16 + q*4;   // local row within tile
            const int ncol = n0 + wn*64 + j*16 + r;
            #pragma unroll
            for (int t = 0; t < 4; t++) {
                const int lr = lr0 + t;
                const int mm = grow0 + lr;          // global row
                const int cr = rr0 + lr;            // chunk-local row
                const float v = acc[i][j][t];
                if (EPI == 0) {
                    if (ncol < 1024) {
                        xin[(size_t)mm*1024 + ncol] = v;
                    } else if (ncol < 2048) {
                        float z = v + bdt[ncol - 1024];
                        dlt[(size_t)mm*1024 + (ncol - 1024)] = (z > 20.f) ? z : log1pf(__expf(z));
                    } else if (ncol < 34816) {
                        Bout[(size_t)cr*32768 + (ncol - 2048)] = f2bf(v);
                    } else {
                        Cout[(size_t)cr*32768 + (ncol - 34816)] = f2bf(v);
                    }
                } else {
                    outf[(size_t)mm*N + ncol] = v;
                }
            }
        }
    }
}

// ================= segmented scan =================
// SC1: per (b,e) group and segment: local scan from h=0, record h_loc and
//      a_prod (32-dim each). grid: (256, SEG) blocks x 256 thr.
__global__ __launch_bounds__(256)
void scan_seg1(const float* __restrict__ dlt, const float* __restrict__ xin,
               const unsigned short* __restrict__ Bbf,
               const float* __restrict__ A_log,
               float* __restrict__ sc_h, float* __restrict__ sc_a,
               int t0, int Tchunk, int SEG, int Tg) {
    const int tid = threadIdx.x;
    const int g = tid >> 5;
    const int s = tid & 31;
    const int G = blockIdx.x * 8 + g;        // 0..2047 (b,e)
    const int seg = blockIdx.y;
    const int b = G >> 10, e = G & 1023;

    const float Aes = -__expf(A_log[e*32 + s]);
    float h = 0.f, ap = 1.f;

    const int lt0 = seg * Tg;                      // chunk-local start
    const size_t rowBC = (size_t)b*Tchunk*32768 + (size_t)e*32 + s;
    const size_t rowDX = (size_t)b*1024*1024 + e;

    const int CH = 8;
    float db[CH], xb[CH], bv[CH];
    #pragma unroll
    for (int j = 0; j < CH; j++) {
        db[j] = dlt[rowDX + (size_t)(t0 + lt0 + j)*1024];
        xb[j] = xin[rowDX + (size_t)(t0 + lt0 + j)*1024];
        bv[j] = bf2f(Bbf[rowBC + (size_t)(lt0 + j)*32768]);
    }
    for (int tc = 0; tc < Tg; tc += CH) {
        float ndb[CH], nxb[CH], nbv[CH];
        const bool more = (tc + CH) < Tg;
        if (more) {
            #pragma unroll
            for (int j = 0; j < CH; j++) {
                const size_t lt2 = lt0 + tc + CH + j;
                ndb[j] = dlt[rowDX + (t0 + lt2)*1024];
                nxb[j] = xin[rowDX + (t0 + lt2)*1024];
                nbv[j] = bf2f(Bbf[rowBC + lt2*32768]);
            }
        }
        #pragma unroll
        for (int j = 0; j < CH; j++) {
            const float a = __expf(db[j] * Aes);
            h = a*h + bv[j]*xb[j];
            ap *= a;
        }
        if (more) {
            #pragma unroll
            for (int j = 0; j < CH; j++) { db[j]=ndb[j]; xb[j]=nxb[j]; bv[j]=nbv[j]; }
        }
    }
    sc_h[((size_t)G*SEG + seg)*32 + s] = h;
    sc_a[((size_t)G*SEG + seg)*32 + s] = ap;
}

// SC2: compose segment boundaries sequentially (SEG steps). 65536 threads.
__global__ __launch_bounds__(256)
void scan_seg2(const float* __restrict__ sc_h, const float* __restrict__ sc_a,
               float* __restrict__ sc_hin, float* __restrict__ hbuf,
               int SEG, int first) {
    const int idx = blockIdx.x * 256 + threadIdx.x;   // 0..65535 = G*32+s
    float h = first ? 0.f : hbuf[idx];
    const int G = idx >> 5, s = idx & 31;
    for (int seg = 0; seg < SEG; seg++) {
        const size_t o = ((size_t)G*SEG + seg)*32 + s;
        sc_hin[o] = h;
        h = sc_h[o] + sc_a[o]*h;
    }
    hbuf[idx] = h;
}

// SC3: re-scan each segment with correct h_in; emit y (SiLU) as bf16.
__global__ __launch_bounds__(256)
void scan_seg3(const float* __restrict__ dlt, const float* __restrict__ xin,
               const unsigned short* __restrict__ Bbf, const unsigned short* __restrict__ Cbf,
               const float* __restrict__ A_log, const float* __restrict__ sc_hin,
               unsigned short* __restrict__ Ybf,
               int t0, int Tchunk, int SEG, int Tg) {
    const int tid = threadIdx.x;
    const int g = tid >> 5;
    const int s = tid & 31;
    const int G = blockIdx.x * 8 + g;
    const int seg = blockIdx.y;
    const int b = G >> 10, e = G & 1023;

    const float Aes = -__expf(A_log[e*32 + s]);
    float h = sc_hin[((size_t)G*SEG + seg)*32 + s];

    const int lt0 = seg * Tg;
    const size_t rowBC = (size_t)b*Tchunk*32768 + (size_t)e*32 + s;
    const size_t rowDX = (size_t)b*1024*1024 + e;

    const int CH = 8;
    float db[CH], xb[CH], bv[CH], cv[CH];
    #pragma unroll
    for (int j = 0; j < CH; j++) {
        db[j] = dlt[rowDX + (size_t)(t0 + lt0 + j)*1024];
        xb[j] = xin[rowDX + (size_t)(t0 + lt0 + j)*1024];
        bv[j] = bf2f(Bbf[rowBC + (size_t)(lt0 + j)*32768]);
        cv[j] = bf2f(Cbf[rowBC + (size_t)(lt0 + j)*32768]);
    }
    for (int tc = 0; tc < Tg; tc += CH) {
        float ndb[CH], nxb[CH], nbv[CH], ncv[CH];
        const bool more = (tc + CH) < Tg;
        if (more) {
            #pragma unroll
            for (int j = 0; j < CH; j++) {
                const size_t lt2 = lt0 + tc + CH + j;
                ndb[j] = dlt[rowDX + (t0 + lt2)*1024];
                nxb[j] = xin[rowDX + (t0 + lt2)*1024];
                nbv[j] = bf2f(Bbf[rowBC + lt2*32768]);
                ncv[j] = bf2f(Cbf[rowBC + lt2*32768]);
            }
        }
        #pragma unroll
        for (int j = 0; j < CH; j++) {
            const float a = __expf(db[j] * Aes);
            h = a*h + bv[j]*xb[j];
            float p = cv[j]*h;
            p += __shfl_xor(p, 16, 32);
            p += __shfl_xor(p, 8, 32);
            p += __shfl_xor(p, 4, 32);
            p += __shfl_xor(p, 2, 32);
            p += __shfl_xor(p, 1, 32);
            if (s == 0) {
                const float y = p / (1.f + __expf(-p));  // SiLU
                Ybf[rowDX + (size_t)(t0 + lt0 + tc + j)*1024] = f2bf(y);
            }
        }
        if (more) {
            #pragma unroll
            for (int j = 0; j < CH; j++) { db[j]=ndb[j]; xb[j]=nxb[j]; bv[j]=nbv[j]; cv[j]=ncv[j]; }
        }
    }
}

// ---------------- launch ----------------
extern "C" void kernel_launch(void* const* d_in, const int* in_sizes, int n_in,
                              void* d_out, int out_size, void* d_ws, size_t ws_size,
                              hipStream_t stream) {
    const float* x     = (const float*)d_in[0];
    const float* Wx    = (const float*)d_in[1];
    const float* Wdt   = (const float*)d_in[2];
    const float* bdt   = (const float*)d_in[3];
    const float* A_log = (const float*)d_in[4];
    const float* WB    = (const float*)d_in[5];
    const float* WC    = (const float*)d_in[6];
    const float* Wout  = (const float*)d_in[7];

    // ---- workspace layout (fixed part = 99,876,864 B) ----
    char* ws = (char*)d_ws;
    unsigned short* Wbf    = (unsigned short*)(ws);                 // 69,206,016
    unsigned short* Xbf    = (unsigned short*)(ws + 69206016);      //  2,097,152
    unsigned short* Woutbf = (unsigned short*)(ws + 71303168);      //  1,048,576
    float*          xin    = (float*)        (ws + 72351744);       //  8,388,608
    float*          dlt    = (float*)        (ws + 80740352);       //  8,388,608
    unsigned short* Ybf    = (unsigned short*)(ws + 89128960);      //  4,194,304
    float*          hbuf   = (float*)        (ws + 93323264);       //    262,144
    float*          sc_h   = (float*)        (ws + 93585408);       //  2,097,152 (SEG<=8)
    float*          sc_a   = (float*)        (ws + 95682560);       //  2,097,152
    float*          sc_hin = (float*)        (ws + 97779712);       //  2,097,152
    unsigned short* Bbf    = (unsigned short*)(ws + 99876864);      // T*131072 B each
    const size_t fixedB = 99876864;

    int T = 128;
    const int cands[4] = {1024, 512, 256, 128};
    for (int ci = 0; ci < 4; ci++) {
        if (fixedB + (size_t)2 * cands[ci] * 131072 <= ws_size) { T = cands[ci]; break; }
    }
    unsigned short* Cbf = Bbf + (size_t)T * 65536;

    int SEG = T / 128; if (SEG < 1) SEG = 1; if (SEG > 8) SEG = 8;
    const int Tg = T / SEG;

    cast_all<<<dim3(2048), dim3(256), 0, stream>>>(
        (const float4*)Wx, (const float4*)Wdt, (const float4*)WB, (const float4*)WC,
        (const float4*)x, (const float4*)Wout, Wbf, Xbf, Woutbf);

    const int NC = SEQLEN / T;
    for (int c = 0; c < NC; c++) {
        const int t0 = c * T;
        gemm_bt<0><<<dim3(NPROJ/128, 2*T/128), dim3(256), 0, stream>>>(
            Xbf, Wbf, DMODEL, NPROJ, t0, T, xin, dlt, Bbf, Cbf, bdt, nullptr);
        scan_seg1<<<dim3(256, SEG), dim3(256), 0, stream>>>(
            dlt, xin, Bbf, A_log, sc_h, sc_a, t0, T, SEG, Tg);
        scan_seg2<<<dim3(256), dim3(256), 0, stream>>>(
            sc_h, sc_a, sc_hin, hbuf, SEG, (c == 0) ? 1 : 0);
        scan_seg3<<<dim3(256, SEG), dim3(256), 0, stream>>>(
            dlt, xin, Bbf, Cbf, A_log, sc_hin, Ybf, t0, T, SEG, Tg);
    }

    gemm_bt<1><<<dim3(DMODEL/128, MROWS/128), dim3(256), 0, stream>>>(
        Ybf, Woutbf, DINNER, DMODEL, 0, MROWS, nullptr, nullptr, nullptr, nullptr, nullptr,
        (float*)d_out);
}

// Round 4
// 543.895 us; speedup vs baseline: 1.4568x; 1.1815x over previous
//
#include <hip/hip_runtime.h>

// ---------------- constants ----------------
#define BATCH   2
#define SEQLEN  1024
#define DMODEL  512
#define DSTATE  32
#define DINNER  1024
#define MROWS   (BATCH*SEQLEN)          // 2048
#define NPROJ   (2*DINNER + 2*DINNER*DSTATE)  // 67584

typedef short bf16x8 __attribute__((ext_vector_type(8)));
typedef float f32x4  __attribute__((ext_vector_type(4)));

__device__ __forceinline__ unsigned short f2bf(float f) {
    union { float f; unsigned u; } c; c.f = f;
    unsigned u = c.u;
    u += 0x7fffu + ((u >> 16) & 1u);   // RTNE
    return (unsigned short)(u >> 16);
}
__device__ __forceinline__ float bf2f(unsigned short h) {
    union { unsigned u; float f; } c; c.u = ((unsigned)h) << 16;
    return c.f;
}

// ---------------- cast fp32 -> bf16 (weights concat + x + Wout) ----------------
__global__ void cast_all(const float4* __restrict__ Wx, const float4* __restrict__ Wdt,
                         const float4* __restrict__ WB, const float4* __restrict__ WC,
                         const float4* __restrict__ x,  const float4* __restrict__ Wout,
                         unsigned short* __restrict__ Wbf,
                         unsigned short* __restrict__ Xbf,
                         unsigned short* __restrict__ Woutbf) {
    const long nWx = 131072, nWdt = 131072, nWB = 4194304, nWC = 4194304;
    const long nWall = nWx + nWdt + nWB + nWC;      // 8650752
    const long nX = 262144, nWo = 131072;
    const long total = nWall + nX + nWo;            // 9043968
    for (long u = (long)blockIdx.x * blockDim.x + threadIdx.x; u < total;
         u += (long)gridDim.x * blockDim.x) {
        float4 v; unsigned short* dst;
        if (u < nWall) {
            if (u < nWx)             v = Wx[u];
            else if (u < nWx+nWdt)   v = Wdt[u - nWx];
            else if (u < nWx+nWdt+nWB) v = WB[u - nWx - nWdt];
            else                     v = WC[u - nWx - nWdt - nWB];
            dst = Wbf + u*4;
        } else if (u < nWall + nX) {
            v = x[u - nWall];       dst = Xbf + (u - nWall)*4;
        } else {
            v = Wout[u - nWall - nX]; dst = Woutbf + (u - nWall - nX)*4;
        }
        ushort4 o; o.x = f2bf(v.x); o.y = f2bf(v.y); o.z = f2bf(v.z); o.w = f2bf(v.w);
        *(ushort4*)dst = o;
    }
}

// ---------------- bf16 MFMA GEMM: C[rows,N] = A[rows,K] * Bw[N,K]^T ----------------
// 128x128 tile, BK=32, 4 waves (2x2). XCD band swizzle + 2-phase double-buffered
// pipeline with counted vmcnt(4): tile t+1's global_load_lds stay in flight
// across the barrier while tile t computes (T3-min + T4 per cdna guide).
template<int EPI>
__global__ __launch_bounds__(256)
void gemm_bt(const unsigned short* __restrict__ A, const unsigned short* __restrict__ Bw,
             int K, int N, int t0, int Tchunk,
             float* __restrict__ xin, float* __restrict__ dlt,
             unsigned short* __restrict__ Bout, unsigned short* __restrict__ Cout,
             const float* __restrict__ bdt, float* __restrict__ outf) {
    __shared__ unsigned short Asm[2][128*32];
    __shared__ unsigned short Bsm[2][128*32];
    const int tid  = threadIdx.x;
    const int w    = tid >> 6;
    const int lane = tid & 63;
    const int wm   = w >> 1, wn = w & 1;

    // ---- XCD band swizzle ----
    const int nx = gridDim.x, ny = gridDim.y;
    int ntile, rtile;
    if ((nx & 7) == 0) {
        const int lin = blockIdx.x + nx * blockIdx.y;
        const int xcd = lin & 7;
        const int sl  = lin >> 3;
        ntile = xcd * (nx >> 3) + sl / ny;
        rtile = sl % ny;
    } else {
        ntile = blockIdx.x; rtile = blockIdx.y;
    }

    const int rr0  = rtile * 128;                 // chunk-local row base of tile
    const int bb   = (rr0 >= Tchunk) ? 1 : 0;
    const int grow0 = bb * SEQLEN + t0 + (rr0 - bb * Tchunk);  // global row base
    const int n0   = ntile * 128;

    f32x4 acc[4][4] = {};

    const unsigned short* Ag = A  + (size_t)grow0 * K;
    const unsigned short* Bg = Bw + (size_t)n0 * K;

    const int c0 = w*64 + lane;       // chunk ids (16B units)
    const int c1 = c0 + 256;
    const int r   = lane & 15;
    const int h16 = lane >> 4;

    const int nt = K >> 5;            // K/32 iterations

    // stage tile k0 into buffer buf (4 x global_load_lds dwordx4 per thread-slot)
    #define STAGE(k0_, buf_)                                                              \
        do {                                                                              \
            __builtin_amdgcn_global_load_lds(                                             \
                (const __attribute__((address_space(1))) void*)(Ag + (size_t)(c0>>2)*K + (k0_) + (c0&3)*8), \
                (__attribute__((address_space(3))) void*)(&Asm[(buf_)][w*512]), 16, 0, 0);\
            __builtin_amdgcn_global_load_lds(                                             \
                (const __attribute__((address_space(1))) void*)(Ag + (size_t)(c1>>2)*K + (k0_) + (c1&3)*8), \
                (__attribute__((address_space(3))) void*)(&Asm[(buf_)][2048 + w*512]), 16, 0, 0); \
            __builtin_amdgcn_global_load_lds(                                             \
                (const __attribute__((address_space(1))) void*)(Bg + (size_t)(c0>>2)*K + (k0_) + (c0&3)*8), \
                (__attribute__((address_space(3))) void*)(&Bsm[(buf_)][w*512]), 16, 0, 0);\
            __builtin_amdgcn_global_load_lds(                                             \
                (const __attribute__((address_space(1))) void*)(Bg + (size_t)(c1>>2)*K + (k0_) + (c1&3)*8), \
                (__attribute__((address_space(3))) void*)(&Bsm[(buf_)][2048 + w*512]), 16, 0, 0); \
        } while (0)

    #define COMPUTE(buf_)                                                                 \
        do {                                                                              \
            bf16x8 af[4], bfr[4];                                                         \
            _Pragma("unroll")                                                             \
            for (int i = 0; i < 4; i++) {                                                 \
                af[i]  = *(const bf16x8*)(&Asm[(buf_)][(wm*64 + i*16 + r)*32 + h16*8]);   \
                bfr[i] = *(const bf16x8*)(&Bsm[(buf_)][(wn*64 + i*16 + r)*32 + h16*8]);   \
            }                                                                             \
            _Pragma("unroll")                                                             \
            for (int i = 0; i < 4; i++)                                                   \
                _Pragma("unroll")                                                         \
                for (int j = 0; j < 4; j++)                                               \
                    acc[i][j] = __builtin_amdgcn_mfma_f32_16x16x32_bf16(af[i], bfr[j], acc[i][j], 0, 0, 0); \
        } while (0)

    STAGE(0, 0);
    for (int it = 0; it < nt - 1; ++it) {
        const int cur = it & 1;
        STAGE((it + 1) * 32, cur ^ 1);
        asm volatile("s_waitcnt vmcnt(4)" ::: "memory");   // old 4 landed; new 4 in flight
        __builtin_amdgcn_s_barrier();
        COMPUTE(cur);
        asm volatile("" ::: "memory");
        __builtin_amdgcn_s_barrier();                      // protect buf cur from next stage
        asm volatile("" ::: "memory");
    }
    asm volatile("s_waitcnt vmcnt(0)" ::: "memory");
    __builtin_amdgcn_s_barrier();
    COMPUTE((nt - 1) & 1);

    #undef STAGE
    #undef COMPUTE

    // epilogue: C/D layout col=lane&15, row=(lane>>4)*4+reg
    const int q = lane >> 4;
    #pragma unroll
    for (int i = 0; i < 4; i++) {
        #pragma unroll
        for (int j = 0; j < 4; j++) {
            const int lr0  = wm*64 + i*16 + q*4;   // local row within tile
            const int ncol = n0 + wn*64 + j*16 + r;
            #pragma unroll
            for (int t = 0; t < 4; t++) {
                const int lr = lr0 + t;
                const int mm = grow0 + lr;          // global row
                const int cr = rr0 + lr;            // chunk-local row
                const float v = acc[i][j][t];
                if (EPI == 0) {
                    if (ncol < 1024) {
                        xin[(size_t)mm*1024 + ncol] = v;
                    } else if (ncol < 2048) {
                        float z = v + bdt[ncol - 1024];
                        dlt[(size_t)mm*1024 + (ncol - 1024)] = (z > 20.f) ? z : log1pf(__expf(z));
                    } else if (ncol < 34816) {
                        Bout[(size_t)cr*32768 + (ncol - 2048)] = f2bf(v);
                    } else {
                        Cout[(size_t)cr*32768 + (ncol - 34816)] = f2bf(v);
                    }
                } else {
                    outf[(size_t)mm*N + ncol] = v;
                }
            }
        }
    }
}

// ================= segmented scan =================
// SC1: per (b,e) group and segment: local scan from h=0, record h_loc and
//      a_prod (32-dim each). grid: (256, SEG) blocks x 256 thr.
__global__ __launch_bounds__(256)
void scan_seg1(const float* __restrict__ dlt, const float* __restrict__ xin,
               const unsigned short* __restrict__ Bbf,
               const float* __restrict__ A_log,
               float* __restrict__ sc_h, float* __restrict__ sc_a,
               int t0, int Tchunk, int SEG, int Tg) {
    const int tid = threadIdx.x;
    const int g = tid >> 5;
    const int s = tid & 31;
    const int G = blockIdx.x * 8 + g;        // 0..2047 (b,e)
    const int seg = blockIdx.y;
    const int b = G >> 10, e = G & 1023;

    const float Aes = -__expf(A_log[e*32 + s]);
    float h = 0.f, ap = 1.f;

    const int lt0 = seg * Tg;                      // chunk-local start
    const size_t rowBC = (size_t)b*Tchunk*32768 + (size_t)e*32 + s;
    const size_t rowDX = (size_t)b*1024*1024 + e;

    const int CH = 8;
    float db[CH], xb[CH], bv[CH];
    #pragma unroll
    for (int j = 0; j < CH; j++) {
        db[j] = dlt[rowDX + (size_t)(t0 + lt0 + j)*1024];
        xb[j] = xin[rowDX + (size_t)(t0 + lt0 + j)*1024];
        bv[j] = bf2f(Bbf[rowBC + (size_t)(lt0 + j)*32768]);
    }
    for (int tc = 0; tc < Tg; tc += CH) {
        float ndb[CH], nxb[CH], nbv[CH];
        const bool more = (tc + CH) < Tg;
        if (more) {
            #pragma unroll
            for (int j = 0; j < CH; j++) {
                const size_t lt2 = lt0 + tc + CH + j;
                ndb[j] = dlt[rowDX + (t0 + lt2)*1024];
                nxb[j] = xin[rowDX + (t0 + lt2)*1024];
                nbv[j] = bf2f(Bbf[rowBC + lt2*32768]);
            }
        }
        #pragma unroll
        for (int j = 0; j < CH; j++) {
            const float a = __expf(db[j] * Aes);
            h = a*h + bv[j]*xb[j];
            ap *= a;
        }
        if (more) {
            #pragma unroll
            for (int j = 0; j < CH; j++) { db[j]=ndb[j]; xb[j]=nxb[j]; bv[j]=nbv[j]; }
        }
    }
    sc_h[((size_t)G*SEG + seg)*32 + s] = h;
    sc_a[((size_t)G*SEG + seg)*32 + s] = ap;
}

// SC2: compose segment boundaries sequentially (SEG steps). 65536 threads.
__global__ __launch_bounds__(256)
void scan_seg2(const float* __restrict__ sc_h, const float* __restrict__ sc_a,
               float* __restrict__ sc_hin, float* __restrict__ hbuf,
               int SEG, int first) {
    const int idx = blockIdx.x * 256 + threadIdx.x;   // 0..65535 = G*32+s
    float h = first ? 0.f : hbuf[idx];
    const int G = idx >> 5, s = idx & 31;
    for (int seg = 0; seg < SEG; seg++) {
        const size_t o = ((size_t)G*SEG + seg)*32 + s;
        sc_hin[o] = h;
        h = sc_h[o] + sc_a[o]*h;
    }
    hbuf[idx] = h;
}

// SC3: re-scan each segment with correct h_in; emit y (SiLU) as bf16.
__global__ __launch_bounds__(256)
void scan_seg3(const float* __restrict__ dlt, const float* __restrict__ xin,
               const unsigned short* __restrict__ Bbf, const unsigned short* __restrict__ Cbf,
               const float* __restrict__ A_log, const float* __restrict__ sc_hin,
               unsigned short* __restrict__ Ybf,
               int t0, int Tchunk, int SEG, int Tg) {
    const int tid = threadIdx.x;
    const int g = tid >> 5;
    const int s = tid & 31;
    const int G = blockIdx.x * 8 + g;
    const int seg = blockIdx.y;
    const int b = G >> 10, e = G & 1023;

    const float Aes = -__expf(A_log[e*32 + s]);
    float h = sc_hin[((size_t)G*SEG + seg)*32 + s];

    const int lt0 = seg * Tg;
    const size_t rowBC = (size_t)b*Tchunk*32768 + (size_t)e*32 + s;
    const size_t rowDX = (size_t)b*1024*1024 + e;

    const int CH = 8;
    float db[CH], xb[CH], bv[CH], cv[CH];
    #pragma unroll
    for (int j = 0; j < CH; j++) {
        db[j] = dlt[rowDX + (size_t)(t0 + lt0 + j)*1024];
        xb[j] = xin[rowDX + (size_t)(t0 + lt0 + j)*1024];
        bv[j] = bf2f(Bbf[rowBC + (size_t)(lt0 + j)*32768]);
        cv[j] = bf2f(Cbf[rowBC + (size_t)(lt0 + j)*32768]);
    }
    for (int tc = 0; tc < Tg; tc += CH) {
        float ndb[CH], nxb[CH], nbv[CH], ncv[CH];
        const bool more = (tc + CH) < Tg;
        if (more) {
            #pragma unroll
            for (int j = 0; j < CH; j++) {
                const size_t lt2 = lt0 + tc + CH + j;
                ndb[j] = dlt[rowDX + (t0 + lt2)*1024];
                nxb[j] = xin[rowDX + (t0 + lt2)*1024];
                nbv[j] = bf2f(Bbf[rowBC + lt2*32768]);
                ncv[j] = bf2f(Cbf[rowBC + lt2*32768]);
            }
        }
        #pragma unroll
        for (int j = 0; j < CH; j++) {
            const float a = __expf(db[j] * Aes);
            h = a*h + bv[j]*xb[j];
            float p = cv[j]*h;
            p += __shfl_xor(p, 16, 32);
            p += __shfl_xor(p, 8, 32);
            p += __shfl_xor(p, 4, 32);
            p += __shfl_xor(p, 2, 32);
            p += __shfl_xor(p, 1, 32);
            if (s == 0) {
                const float y = p / (1.f + __expf(-p));  // SiLU
                Ybf[rowDX + (size_t)(t0 + lt0 + tc + j)*1024] = f2bf(y);
            }
        }
        if (more) {
            #pragma unroll
            for (int j = 0; j < CH; j++) { db[j]=ndb[j]; xb[j]=nxb[j]; bv[j]=nbv[j]; cv[j]=ncv[j]; }
        }
    }
}

// ---------------- launch ----------------
extern "C" void kernel_launch(void* const* d_in, const int* in_sizes, int n_in,
                              void* d_out, int out_size, void* d_ws, size_t ws_size,
                              hipStream_t stream) {
    const float* x     = (const float*)d_in[0];
    const float* Wx    = (const float*)d_in[1];
    const float* Wdt   = (const float*)d_in[2];
    const float* bdt   = (const float*)d_in[3];
    const float* A_log = (const float*)d_in[4];
    const float* WB    = (const float*)d_in[5];
    const float* WC    = (const float*)d_in[6];
    const float* Wout  = (const float*)d_in[7];

    // ---- workspace layout (fixed part = 99,876,864 B) ----
    char* ws = (char*)d_ws;
    unsigned short* Wbf    = (unsigned short*)(ws);                 // 69,206,016
    unsigned short* Xbf    = (unsigned short*)(ws + 69206016);      //  2,097,152
    unsigned short* Woutbf = (unsigned short*)(ws + 71303168);      //  1,048,576
    float*          xin    = (float*)        (ws + 72351744);       //  8,388,608
    float*          dlt    = (float*)        (ws + 80740352);       //  8,388,608
    unsigned short* Ybf    = (unsigned short*)(ws + 89128960);      //  4,194,304
    float*          hbuf   = (float*)        (ws + 93323264);       //    262,144
    float*          sc_h   = (float*)        (ws + 93585408);       //  2,097,152 (SEG<=8)
    float*          sc_a   = (float*)        (ws + 95682560);       //  2,097,152
    float*          sc_hin = (float*)        (ws + 97779712);       //  2,097,152
    unsigned short* Bbf    = (unsigned short*)(ws + 99876864);      // T*131072 B each
    const size_t fixedB = 99876864;

    int T = 128;
    const int cands[4] = {1024, 512, 256, 128};
    for (int ci = 0; ci < 4; ci++) {
        if (fixedB + (size_t)2 * cands[ci] * 131072 <= ws_size) { T = cands[ci]; break; }
    }
    unsigned short* Cbf = Bbf + (size_t)T * 65536;

    const int SEG = 8;
    const int Tg = T / SEG;

    cast_all<<<dim3(2048), dim3(256), 0, stream>>>(
        (const float4*)Wx, (const float4*)Wdt, (const float4*)WB, (const float4*)WC,
        (const float4*)x, (const float4*)Wout, Wbf, Xbf, Woutbf);

    const int NC = SEQLEN / T;
    for (int c = 0; c < NC; c++) {
        const int t0 = c * T;
        gemm_bt<0><<<dim3(NPROJ/128, 2*T/128), dim3(256), 0, stream>>>(
            Xbf, Wbf, DMODEL, NPROJ, t0, T, xin, dlt, Bbf, Cbf, bdt, nullptr);
        scan_seg1<<<dim3(256, SEG), dim3(256), 0, stream>>>(
            dlt, xin, Bbf, A_log, sc_h, sc_a, t0, T, SEG, Tg);
        scan_seg2<<<dim3(256), dim3(256), 0, stream>>>(
            sc_h, sc_a, sc_hin, hbuf, SEG, (c == 0) ? 1 : 0);
        scan_seg3<<<dim3(256, SEG), dim3(256), 0, stream>>>(
            dlt, xin, Bbf, Cbf, A_log, sc_hin, Ybf, t0, T, SEG, Tg);
    }

    gemm_bt<1><<<dim3(DMODEL/128, MROWS/128), dim3(256), 0, stream>>>(
        Ybf, Woutbf, DINNER, DMODEL, 0, MROWS, nullptr, nullptr, nullptr, nullptr, nullptr,
        (float*)d_out);
}